// Round 15
// baseline (1072.053 us; speedup 1.0000x reference)
//
#include <hip/hip_runtime.h>
#include <hip/hip_bf16.h>
#include <stdint.h>

typedef __attribute__((ext_vector_type(8))) short bf16x8;
typedef __attribute__((ext_vector_type(4))) float f32x4;
typedef __attribute__((ext_vector_type(4))) int i32x4;

constexpr int Mdim = 8192;
constexpr int Ndim = 11008;
constexpr int Kdim = 4096;
constexpr int NT = Kdim / 64;                       // 64 K-tiles of BK=64
constexpr int NWG = (Mdim / 256) * (Ndim / 256);    // 1376
constexpr int CPX = NWG / 8;                        // 172
constexpr int NBN = Ndim / 256;                     // 43

__device__ __forceinline__ unsigned short f2bf(float f) {
    __bf16 h = (__bf16)f;
    return __builtin_bit_cast(unsigned short, h);
}

__device__ __forceinline__ void gload16(const void* g, void* lds) {
    __builtin_amdgcn_global_load_lds(
        (const __attribute__((address_space(1))) unsigned int*)g,
        (__attribute__((address_space(3))) unsigned int*)lds,
        16, 0, 0);
}

// ---------------- prepass 1 (fused): A fp32->i8 per-row  ||  per-col fold factors ----------------
__global__ __launch_bounds__(256) void prepAS_kernel(const float* __restrict__ A,
                                                     char* __restrict__ Aq,
                                                     float* __restrict__ sA,
                                                     const float* __restrict__ Ws,
                                                     float* __restrict__ Fc,
                                                     float* __restrict__ sCol)
{
    const int tid = threadIdx.x;
    if (blockIdx.x >= Mdim) {
        const int n = (blockIdx.x - Mdim) * 256 + tid;     // 43*256 = 11008 exact
        float mx = 0.f;
        for (int g = 0; g < 128; ++g) mx = fmaxf(mx, Ws[(size_t)g * Ndim + n]);
        Fc[n]   = 15.875f / mx;                            // 127/(8*mx)
        sCol[n] = mx * (8.0f / 127.0f);
        return;
    }
    __shared__ float red[4];
    const int row = blockIdx.x;
    const float* src = A + (size_t)row * Kdim + tid * 16;
    f32x4 v[4];
    float m = 0.f;
#pragma unroll
    for (int j = 0; j < 4; ++j) {
        v[j] = *(const f32x4*)(src + j * 4);
#pragma unroll
        for (int e = 0; e < 4; ++e) m = fmaxf(m, fabsf(v[j][e]));
    }
#pragma unroll
    for (int o = 32; o > 0; o >>= 1) m = fmaxf(m, __shfl_down(m, o));
    if ((tid & 63) == 0) red[tid >> 6] = m;
    __syncthreads();
    m = fmaxf(fmaxf(red[0], red[1]), fmaxf(red[2], red[3]));
    const float inv = 127.0f / m;
    if (tid == 0) sA[row] = m * (1.0f / 127.0f);
    char out[16];
#pragma unroll
    for (int j = 0; j < 4; ++j)
#pragma unroll
        for (int e = 0; e < 4; ++e)
            out[j * 4 + e] = (char)__float2int_rn(v[j][e] * inv);
    *(i32x4*)(Aq + (size_t)row * Kdim + tid * 16) = *(const i32x4*)out;
}

// ---------------- prepass 2: W int4 -> i8 (scale-folded), transposed [N][K] ----------------
__global__ __launch_bounds__(256) void wq_kernel(const int* __restrict__ Wq,
                                                 const float* __restrict__ Ws,
                                                 const float* __restrict__ Fc,
                                                 char* __restrict__ Wt)
{
    __shared__ char T[64][80];
    const int kt = blockIdx.x % (Kdim / 64);
    const int nt = blockIdx.x / (Kdim / 64);
    const int k0 = kt * 64, n0 = nt * 64;
    const int t = threadIdx.x;

    const int pr   = t >> 3;
    const int nloc = (t & 7) * 8;
    const int* wp = Wq + (size_t)(k0 / 2 + pr) * Ndim + n0 + nloc;
    const i32x4 ra = *(const i32x4*)wp;
    const i32x4 rb = *(const i32x4*)(wp + 4);
    const int g = (k0 + 2 * pr) >> 5;
    const float* sp = Ws + (size_t)g * Ndim + n0 + nloc;
    const f32x4 s0 = *(const f32x4*)sp;
    const f32x4 s1 = *(const f32x4*)(sp + 4);
    const f32x4 f0 = *(const f32x4*)(Fc + n0 + nloc);
    const f32x4 f1 = *(const f32x4*)(Fc + n0 + nloc + 4);
#pragma unroll
    for (int i = 0; i < 8; ++i) {
        const int v = (i < 4) ? ra[i] : rb[i - 4];
        const float sf = ((i < 4) ? s0[i] : s1[i - 4]) * ((i < 4) ? f0[i] : f1[i - 4]);
        T[nloc + i][2 * pr]     = (char)__float2int_rn((float)((v & 15) - 8) * sf);
        T[nloc + i][2 * pr + 1] = (char)__float2int_rn((float)(((v >> 4) & 15) - 8) * sf);
    }
    __syncthreads();
    const int nl = t >> 2;
    const int ko = (t & 3) * 16;
    const i32x4 o = *(const i32x4*)&T[nl][ko];
    *(i32x4*)(Wt + (size_t)(n0 + nl) * Kdim + k0 + ko) = o;
}

// ---- main GEMM: 256x256x64, 4 waves (128x128 each), 1 wave/SIMD, 4-deep LDS pipeline ----
__global__ __launch_bounds__(256, 1) void gemm_i8_kernel(
    const char* __restrict__ Ab,
    const char* __restrict__ Bt,
    const float* __restrict__ sA,
    const float* __restrict__ sCol,
    const float* __restrict__ Bias,
    float* __restrict__ Out)
{
    // A: 4 slots x 16KB at 0; B: 4 slots x 16KB at 65536. 128 KiB.
    __shared__ char sh[131072];

    const int tid  = threadIdx.x;
    const int lane = tid & 63;
    const int wid  = tid >> 6;               // 0..3
    const int wr   = wid >> 1;               // 0..1 : M 128-row half
    const int wc   = wid & 1;                // 0..1 : N 128-col half
    const int l15  = lane & 15;
    const int l4   = lane >> 4;
    // quarter-wave bank swizzle (verified 0-conflict in R14): phys slot = l4 ^ ((row>>1)&3)
    const int rcol = ((l4 ^ ((l15 >> 1) & 3)) << 4);

    // XCD-aware bijective swizzle, bm-major chunks per XCD
    const int wg  = ((int)blockIdx.x % 8) * CPX + (int)blockIdx.x / 8;
    const int bm = wg / NBN, bn = wg % NBN;
    const int m0 = bm * 256, n0 = bn * 256;

    // staging: thread covers row (tid>>2)+64j, phys slot tid&3, source chunk pre-swizzled
    const int sr   = tid >> 2;               // 0..63
    const int sc16 = ((tid & 3) ^ ((tid >> 3) & 3)) * 16;
    const int ldo  = tid * 16;               // linear dest within 4KB chunk
    const char* aSrc = Ab + (size_t)(m0 + sr) * Kdim + sc16;
    const char* bSrc = Bt + (size_t)(n0 + sr) * Kdim + sc16;

    auto stageA = [&](int tt) {              // 4 gloads: rows 0..255
        char* base = &sh[(tt & 3) * 16384 + ldo];
#pragma unroll
        for (int j = 0; j < 4; ++j)
            gload16(aSrc + (size_t)(j * 64) * Kdim + tt * 64, base + j * 4096);
    };
    auto stageB = [&](int tt) {
        char* base = &sh[65536 + (tt & 3) * 16384 + ldo];
#pragma unroll
        for (int j = 0; j < 4; ++j)
            gload16(bSrc + (size_t)(j * 64) * Kdim + tt * 64, base + j * 4096);
    };

#define READF(TT, AF, BF)                                                     \
    {                                                                         \
        const char* as_ = &sh[((TT) & 3) * 16384];                            \
        const char* bs_ = &sh[65536 + ((TT) & 3) * 16384];                    \
        _Pragma("unroll")                                                     \
        for (int f = 0; f < 8; ++f)                                           \
            AF[f] = *(const i32x4*)&as_[(wr * 128 + f * 16 + l15) * 64 + rcol]; \
        _Pragma("unroll")                                                     \
        for (int f = 0; f < 8; ++f)                                           \
            BF[f] = *(const i32x4*)&bs_[(wc * 128 + f * 16 + l15) * 64 + rcol]; \
    }

    i32x4 acc[8][8];
#pragma unroll
    for (int i = 0; i < 8; ++i)
#pragma unroll
        for (int j = 0; j < 8; ++j) acc[i][j] = (i32x4){0, 0, 0, 0};

    // prologue: stage tiles 0,1,2 (24 loads); complete 0,1 (leave 2's 8); barrier; read F0
    stageA(0); stageB(0);
    stageA(1); stageB(1);
    stageA(2); stageB(2);
    asm volatile("s_waitcnt vmcnt(8)" ::: "memory");
    __builtin_amdgcn_s_barrier();

    i32x4 aF0[8], bF0[8], aF1[8], bF1[8];
    READF(0, aF0, bF0);

    // body(t): read F(t+1) [slot staged+barriered at end of t-1]; DMA t+3; 64 MFMA on F(t);
    // end: vmcnt(8) completes DMA(t+2) [outstanding = DMA(t+2)+DMA(t+3)]; barrier.
#define BODY(T, CA, CB, NA, NB)                                               \
    {                                                                         \
        if ((T) + 1 < NT) READF((T) + 1, NA, NB);                             \
        if ((T) + 3 < NT) { stageA((T) + 3); stageB((T) + 3); }               \
        _Pragma("unroll")                                                     \
        for (int fm = 0; fm < 8; ++fm) {                                      \
            _Pragma("unroll")                                                 \
            for (int fn = 0; fn < 8; ++fn)                                    \
                acc[fm][fn] = __builtin_amdgcn_mfma_i32_16x16x64_i8(          \
                    CA[fm], CB[fn], acc[fm][fn], 0, 0, 0);                    \
        }                                                                     \
        if ((T) <= NT - 4)      asm volatile("s_waitcnt vmcnt(8)" ::: "memory"); \
        else if ((T) == NT - 3) asm volatile("s_waitcnt vmcnt(0)" ::: "memory"); \
        asm volatile("" ::: "memory");                                        \
        __builtin_amdgcn_s_barrier();                                         \
    }

    for (int t2 = 0; t2 < NT; t2 += 2) {
        BODY(t2,     aF0, bF0, aF1, bF1);
        BODY(t2 + 1, aF1, bF1, aF0, bF0);
    }

    // ---- epilogue: out = sA[m]*sCol[n]*acc + bias; C/D col=lane&15, row=(lane>>4)*4+r ----
    const int rb = l4 * 4;
    float sc[8], bb[8];
#pragma unroll
    for (int fn = 0; fn < 8; ++fn) {
        const int ng = n0 + wc * 128 + fn * 16 + l15;
        sc[fn] = sCol[ng];
        bb[fn] = Bias[ng];
    }
#pragma unroll
    for (int fm = 0; fm < 8; ++fm) {
        const size_t mg = (size_t)(m0 + wr * 128 + fm * 16 + rb);
#pragma unroll
        for (int r = 0; r < 4; ++r) {
            const float sa = sA[mg + r];
#pragma unroll
            for (int fn = 0; fn < 8; ++fn) {
                const int ng = n0 + wc * 128 + fn * 16 + l15;
                __builtin_nontemporal_store((float)acc[fm][fn][r] * sa * sc[fn] + bb[fn],
                                            &Out[(mg + r) * Ndim + ng]);
            }
        }
    }
#undef READF
#undef BODY
}

// ---------------- fallback: fused bf16 kernel (if ws too small) ----------------
constexpr int SA = 72;
__global__ __launch_bounds__(256) void w4a32_fused_kernel(
    const float* __restrict__ A,
    const int* __restrict__ Wq,
    const float* __restrict__ Ws,
    const float* __restrict__ Bias,
    float* __restrict__ Out)
{
    __shared__ unsigned short As[128 * SA];
    __shared__ unsigned short Bs[128 * SA];
    const int tid = threadIdx.x;
    const int nbn = Ndim / 128;
    const int bn = blockIdx.x % nbn;
    const int bm = blockIdx.x / nbn;
    const int m0 = bm * 128, n0 = bn * 128;
    const int lane = tid & 63;
    const int wid  = tid >> 6;
    const int wr   = wid >> 1;
    const int wc   = wid & 1;
    const int l15  = lane & 15;
    const int l4   = lane >> 4;
    f32x4 acc[4][4];
#pragma unroll
    for (int i = 0; i < 4; ++i)
#pragma unroll
        for (int j = 0; j < 4; ++j) acc[i][j] = (f32x4){0.f, 0.f, 0.f, 0.f};
    const int a_tr = tid >> 3;
    const int a_tc = (tid & 7) * 8;
    const int kp2  = tid >> 4;
    const int n8   = (tid & 15) * 8;
    for (int kt = 0; kt < Kdim / 64; ++kt) {
        const int k0 = kt * 64;
        __syncthreads();
#pragma unroll
        for (int j = 0; j < 4; ++j) {
            const int ml = a_tr + 32 * j;
            const float* src = A + (size_t)(m0 + ml) * Kdim + (k0 + a_tc);
            const f32x4 x0 = *(const f32x4*)src;
            const f32x4 x1 = *(const f32x4*)(src + 4);
            union { bf16x8 v; unsigned short u[8]; } h;
            h.u[0] = f2bf(x0[0]); h.u[1] = f2bf(x0[1]);
            h.u[2] = f2bf(x0[2]); h.u[3] = f2bf(x0[3]);
            h.u[4] = f2bf(x1[0]); h.u[5] = f2bf(x1[1]);
            h.u[6] = f2bf(x1[2]); h.u[7] = f2bf(x1[3]);
            *(bf16x8*)(&As[ml * SA + (a_tc ^ ((ml & 7) << 3))]) = h.v;
        }
        {
            const int pr = kt * 32 + 2 * kp2;
            const int* wp = Wq + (size_t)pr * Ndim + (n0 + n8);
            const i32x4 r0a = *(const i32x4*)wp;
            const i32x4 r0b = *(const i32x4*)(wp + 4);
            const i32x4 r1a = *(const i32x4*)(wp + Ndim);
            const i32x4 r1b = *(const i32x4*)(wp + Ndim + 4);
            const int g = 2 * kt + (kp2 >> 3);
            const float* sp = Ws + (size_t)g * Ndim + (n0 + n8);
            const f32x4 s0 = *(const f32x4*)sp;
            const f32x4 s1 = *(const f32x4*)(sp + 4);
#pragma unroll
            for (int i = 0; i < 8; ++i) {
                const float s = (i < 4) ? s0[i] : s1[i - 4];
                const int b0 = (i < 4) ? r0a[i] : r0b[i - 4];
                const int b1 = (i < 4) ? r1a[i] : r1b[i - 4];
                union { unsigned long long v; unsigned short u[4]; } o;
                o.u[0] = f2bf((float)((b0 & 15) - 8) * s);
                o.u[1] = f2bf((float)(((b0 >> 4) & 15) - 8) * s);
                o.u[2] = f2bf((float)((b1 & 15) - 8) * s);
                o.u[3] = f2bf((float)(((b1 >> 4) & 15) - 8) * s);
                const int nl = n8 + i;
                const int swzz = ((nl ^ (nl >> 3)) & 7) << 3;
                *(unsigned long long*)(&Bs[nl * SA + ((4 * kp2) ^ swzz)]) = o.v;
            }
        }
        __syncthreads();
#pragma unroll
        for (int ks = 0; ks < 2; ++ks) {
            const int kb  = ks * 32 + l4 * 8;
            const int swa = (l15 & 7) << 3;
            bf16x8 af[4], bfr[4];
#pragma unroll
            for (int fm = 0; fm < 4; ++fm) {
                const int row = wr * 64 + fm * 16 + l15;
                af[fm] = *(const bf16x8*)(&As[row * SA + (kb ^ swa)]);
            }
#pragma unroll
            for (int fn = 0; fn < 4; ++fn) {
                const int nrow = wc * 64 + fn * 16 + l15;
                const int swb = ((nrow ^ (nrow >> 3)) & 7) << 3;
                bfr[fn] = *(const bf16x8*)(&Bs[nrow * SA + (kb ^ swb)]);
            }
#pragma unroll
            for (int fm = 0; fm < 4; ++fm)
#pragma unroll
                for (int fn = 0; fn < 4; ++fn)
                    acc[fm][fn] = __builtin_amdgcn_mfma_f32_16x16x32_bf16(
                        af[fm], bfr[fn], acc[fm][fn], 0, 0, 0);
        }
    }
    const int rb = l4 * 4;
    float bv[4];
#pragma unroll
    for (int fn = 0; fn < 4; ++fn)
        bv[fn] = Bias[n0 + wc * 64 + fn * 16 + l15];
#pragma unroll
    for (int fm = 0; fm < 4; ++fm) {
        const size_t mg = (size_t)(m0 + wr * 64 + fm * 16 + rb);
#pragma unroll
        for (int fn = 0; fn < 4; ++fn) {
            const int ng = n0 + wc * 64 + fn * 16 + l15;
            const float b = bv[fn];
#pragma unroll
            for (int r = 0; r < 4; ++r)
                Out[(mg + r) * Ndim + ng] = acc[fm][fn][r] + b;
        }
    }
}

extern "C" void kernel_launch(void* const* d_in, const int* in_sizes, int n_in,
                              void* d_out, int out_size, void* d_ws, size_t ws_size,
                              hipStream_t stream) {
    const float* A    = (const float*)d_in[0];
    const int* Wq     = (const int*)d_in[1];
    const float* Ws   = (const float*)d_in[2];
    const float* Bias = (const float*)d_in[3];
    float* Out        = (float*)d_out;

    const size_t offAq = 0;
    const size_t offWt = (size_t)Mdim * Kdim;                     // 33.5 MB
    const size_t offSA = offWt + (size_t)Ndim * Kdim;             // +45.1 MB
    const size_t offF  = offSA + (size_t)Mdim * 4;
    const size_t offSC = offF + (size_t)Ndim * 4;
    const size_t need  = offSC + (size_t)Ndim * 4;

    if (ws_size >= need) {
        char*  Aq   = (char*)d_ws + offAq;
        char*  Wt   = (char*)d_ws + offWt;
        float* sAp  = (float*)((char*)d_ws + offSA);
        float* Fc   = (float*)((char*)d_ws + offF);
        float* sCol = (float*)((char*)d_ws + offSC);
        prepAS_kernel<<<Mdim + Ndim / 256, 256, 0, stream>>>(A, Aq, sAp, Ws, Fc, sCol);
        wq_kernel<<<(Kdim / 64) * (Ndim / 64), 256, 0, stream>>>(Wq, Ws, Fc, Wt);
        gemm_i8_kernel<<<NWG, 256, 0, stream>>>(Aq, Wt, sAp, sCol, Bias, Out);
    } else {
        w4a32_fused_kernel<<<(Mdim / 128) * (Ndim / 128), 256, 0, stream>>>(A, Wq, Ws, Bias, Out);
    }
}